// Round 17
// baseline (100.632 us; speedup 1.0000x reference)
//
#include <hip/hip_runtime.h>

// TsSub: out[b, p, t] = x[b, I[p], t*10] - x[b, J[p], t*10]
// x: (256, 64, 2000) f32, out: (256, 2016, 200) f32, (I,J)=triu_indices(64,k=1)
//
// R17 = R16 (one block/batch, 1x amplification, load-first staging, full-row
// emit) with ONE change: plain cached stores in emit (was nontemporal).
// Rationale: harness fills sustain 6.76 TB/s with cached WB stores; R11's
// nt-vs-cached A/B was confounded by R8's L2-dependent stage reads. R16's
// structure has zero L2 reliance -> cached streaming is safe; testing
// whether the nt path itself was capping the write phase.

#define NF     64
#define T_OUT  200
#define NPAIR  2016
#define NB     256
#define RF4    500     // vec4 per x row
#define TV4    50      // vec4 per out row
#define NT     1024
#define NSAMP  (NF * T_OUT)   // 12800

typedef float fx4 __attribute__((ext_vector_type(4)));

__global__ __launch_bounds__(NT)
void ts_sub_b(const fx4* __restrict__ xv, fx4* __restrict__ out) {
    __shared__ __attribute__((aligned(16))) float sf[NSAMP];  // 51.2 KB
    __shared__ unsigned char pi[NPAIR];
    __shared__ unsigned char pj[NPAIR];

    const int tid = threadIdx.x;
    const int b   = blockIdx.x;
    const fx4* __restrict__ xb = xv + (size_t)b * (NF * RF4);

    // --- issue ALL stage loads first (sample k: vec4 m=5*(k>>1)+2*(k&1)) ---
    fx4 r0, r1, r2, r3, r4, r5, r6, r7, r8, r9, r10, r11, r12;
    {
        int row = tid / T_OUT;
        int k   = tid - row * T_OUT;
#define LOADIT(RR, IT)                                                        \
        {                                                                     \
            if (IT < 12 || (IT * NT + tid) < NSAMP) {                         \
                RR = __builtin_nontemporal_load(                              \
                         &xb[row * RF4 + 5 * (k >> 1) + 2 * (k & 1)]);        \
            }                                                                 \
            row += 5; k += 24;                     /* 1024 = 5*200 + 24 */    \
            if (k >= T_OUT) { k -= T_OUT; ++row; }                            \
        }
        LOADIT(r0, 0)  LOADIT(r1, 1)  LOADIT(r2, 2)  LOADIT(r3, 3)
        LOADIT(r4, 4)  LOADIT(r5, 5)  LOADIT(r6, 6)  LOADIT(r7, 7)
        LOADIT(r8, 8)  LOADIT(r9, 9)  LOADIT(r10, 10) LOADIT(r11, 11)
        LOADIT(r12, 12)
#undef LOADIT
    }

    // --- pair table while loads are in flight (2 iters/thread) ---
    for (int p = tid; p < NPAIR; p += NT) {
        float d = 16129.0f - 8.0f * (float)p;          // 127^2 - 8p
        int i = (int)((127.0f - sqrtf(d)) * 0.5f);
        if (i < 0) i = 0;
        while (i > 0 && (i * (127 - i)) / 2 > p) --i;
        while (((i + 1) * (126 - i)) / 2 <= p) ++i;
        pi[p] = (unsigned char)i;
        pj[p] = (unsigned char)(p - (i * (127 - i)) / 2 + i + 1);
    }

    // --- extract regs -> LDS ---
    {
        int idx = tid;                     // k parity = idx parity (200 even)
#define EXTRIT(RR, IT)                                                        \
        {                                                                     \
            if (IT < 12 || idx < NSAMP) {                                     \
                sf[idx] = (idx & 1) ? RR.z : RR.x;                            \
            }                                                                 \
            idx += NT;                                                        \
        }
        EXTRIT(r0, 0)  EXTRIT(r1, 1)  EXTRIT(r2, 2)  EXTRIT(r3, 3)
        EXTRIT(r4, 4)  EXTRIT(r5, 5)  EXTRIT(r6, 6)  EXTRIT(r7, 7)
        EXTRIT(r8, 8)  EXTRIT(r9, 9)  EXTRIT(r10, 10) EXTRIT(r11, 11)
        EXTRIT(r12, 12)
#undef EXTRIT
    }
    __syncthreads();

    // --- emit all 2016 pair rows x 50 vec4, PLAIN cached stores ---
    const fx4* __restrict__ s4 = reinterpret_cast<const fx4*>(sf); // stride 50
    fx4* __restrict__ ob = out + (size_t)b * (NPAIR * TV4);

    int p  = tid / TV4;
    int t4 = tid - p * TV4;
    for (int v = tid; v < NPAIR * TV4; v += NT) {        // 100800
        fx4 a = s4[pi[p] * TV4 + t4];
        fx4 c = s4[pj[p] * TV4 + t4];
        ob[(size_t)p * TV4 + t4] = a - c;        // plain store (A/B vs nt)
        p += 20;                                 // 1024 = 20*50 + 24
        t4 += 24;
        if (t4 >= TV4) { t4 -= TV4; ++p; }
    }
}

extern "C" void kernel_launch(void* const* d_in, const int* in_sizes, int n_in,
                              void* d_out, int out_size, void* d_ws, size_t ws_size,
                              hipStream_t stream) {
    const float* x = (const float*)d_in[0];
    float* out = (float*)d_out;
    ts_sub_b<<<dim3(NB), dim3(NT), 0, stream>>>((const fx4*)x, (fx4*)out);
}